// Round 1
// baseline (264.838 us; speedup 1.0000x reference)
//
#include <hip/hip_runtime.h>

#define B_  8
#define C_  64
#define H_  256
#define W_  256
#define REP_ 512
// kern outputs: B_*C_*9 = 4608

__global__ __launch_bounds__(256) void compute_kern_k(const float* __restrict__ rep,
                                                      const float* __restrict__ wkey,
                                                      float* __restrict__ kern) {
    // one wave (64 lanes) per output element (b, o), o in [0,576)
    int wave = blockIdx.x * 4 + (threadIdx.x >> 6);   // 0..4607
    int lane = threadIdx.x & 63;
    int b = wave / 576;
    int o = wave - b * 576;
    const float* wrow = wkey + (size_t)o * REP_;
    const float* rrow = rep  + (size_t)b * REP_;
    float acc = 0.f;
#pragma unroll
    for (int i = 0; i < REP_ / 64; ++i) {
        int r = lane + i * 64;
        acc += rrow[r] * wrow[r];
    }
#pragma unroll
    for (int off = 32; off > 0; off >>= 1)
        acc += __shfl_xor(acc, off, 64);
    if (lane == 0) {
        float v = acc;
        kern[wave] = v > 0.f ? v : 0.1f * v;   // LeakyReLU(0.1)
    }
}

__global__ __launch_bounds__(256) void dwconv3x3_reflect(const float* __restrict__ x,
                                                         const float* __restrict__ kern,
                                                         float* __restrict__ out) {
    // grid: (B_*C_) planes * (H_/4) row-blocks = 512*64 = 32768 blocks
    int plane = blockIdx.x >> 6;          // b*64 + c
    int rb    = blockIdx.x & 63;          // row block: 4 rows each
    int h  = rb * 4 + (threadIdx.x >> 6); // output row
    int c4 = (threadIdx.x & 63) << 2;     // output col start (multiple of 4)

    const float* pin = x + (size_t)plane * (H_ * W_);
    const float* kp  = kern + plane * 9;
    float k[9];
#pragma unroll
    for (int i = 0; i < 9; ++i) k[i] = kp[i];   // block-uniform -> scalar loads

    // reflection-padded row indices (pad=1): -1 -> 1, H -> H-2
    int rows[3];
    rows[0] = (h == 0)      ? 1      : h - 1;
    rows[1] = h;
    rows[2] = (h == H_ - 1) ? H_ - 2 : h + 1;

    // column window c4-1 .. c4+4 with reflection at 0 / W-1
    int li = (c4 == 0)       ? 1      : c4 - 1;
    int ri = (c4 == W_ - 4)  ? W_ - 2 : c4 + 4;

    float v[3][6];
#pragma unroll
    for (int r = 0; r < 3; ++r) {
        const float* rowp = pin + rows[r] * W_;
        float4 mid = *(const float4*)(rowp + c4);
        v[r][1] = mid.x; v[r][2] = mid.y; v[r][3] = mid.z; v[r][4] = mid.w;
        v[r][0] = rowp[li];
        v[r][5] = rowp[ri];
    }

    float4 o4;
    float* op = (float*)&o4;
#pragma unroll
    for (int j = 0; j < 4; ++j) {
        float s = 0.f;
#pragma unroll
        for (int dy = 0; dy < 3; ++dy)
#pragma unroll
            for (int dx = 0; dx < 3; ++dx)
                s += k[dy * 3 + dx] * v[dy][j + dx];
        op[j] = s;
    }
    *(float4*)(out + (size_t)plane * (H_ * W_) + h * W_ + c4) = o4;
}

extern "C" void kernel_launch(void* const* d_in, const int* in_sizes, int n_in,
                              void* d_out, int out_size, void* d_ws, size_t ws_size,
                              hipStream_t stream) {
    const float* x    = (const float*)d_in[0];   // [8,64,256,256]
    const float* rep  = (const float*)d_in[1];   // [8,512]
    const float* wkey = (const float*)d_in[2];   // [576,512]
    float* out  = (float*)d_out;                 // [8,64,256,256]
    float* kern = (float*)d_ws;                  // 4608 floats scratch

    // 4608 waves, 4 waves per 256-thread block
    compute_kern_k<<<1152, 256, 0, stream>>>(rep, wkey, kern);
    // 512 planes * 64 row-blocks
    dwconv3x3_reflect<<<32768, 256, 0, stream>>>(x, kern, out);
}

// Round 2
// 239.684 us; speedup vs baseline: 1.1049x; 1.1049x over previous
//
#include <hip/hip_runtime.h>

#define B_  8
#define C_  64
#define H_  256
#define W_  256
#define REP_ 512
// kern outputs: B_*C_*9 = 4608

__global__ __launch_bounds__(256) void compute_kern_k(const float* __restrict__ rep,
                                                      const float* __restrict__ wkey,
                                                      float* __restrict__ kern) {
    // one wave (64 lanes) per output element (b, o), o in [0,576)
    int wave = blockIdx.x * 4 + (threadIdx.x >> 6);   // 0..4607
    int lane = threadIdx.x & 63;
    int b = wave / 576;
    int o = wave - b * 576;
    const float* wrow = wkey + (size_t)o * REP_;
    const float* rrow = rep  + (size_t)b * REP_;
    float acc = 0.f;
#pragma unroll
    for (int i = 0; i < REP_ / 64; ++i) {
        int r = lane + i * 64;
        acc += rrow[r] * wrow[r];
    }
#pragma unroll
    for (int off = 32; off > 0; off >>= 1)
        acc += __shfl_xor(acc, off, 64);
    if (lane == 0) {
        float v = acc;
        kern[wave] = v > 0.f ? v : 0.1f * v;   // LeakyReLU(0.1)
    }
}

// Each thread: a 4-wide x 16-tall strip. Sliding 3-row register window (ring-4,
// prefetch depth 1). Horizontal halo via cross-lane shuffle, no scalar loads.
__global__ __launch_bounds__(256) void dwconv3x3_strip(const float* __restrict__ x,
                                                       const float* __restrict__ kern,
                                                       float* __restrict__ out) {
    int plane   = blockIdx.x >> 2;          // b*64 + c
    int quarter = blockIdx.x & 3;           // 64-row quarter of the plane
    int wv   = threadIdx.x >> 6;            // wave in block: 16-row strip
    int lane = threadIdx.x & 63;
    int r0 = quarter * 64 + wv * 16;        // first output row of this strip
    int c4 = lane << 2;                     // this lane's 4 columns

    const float* pin  = x   + (size_t)plane * (H_ * W_);
    float*       pout = out + (size_t)plane * (H_ * W_);
    const float* kp   = kern + plane * 9;
    float k[9];
#pragma unroll
    for (int i = 0; i < 9; ++i) k[i] = kp[i];     // block-uniform

    // ring buffer: 4 rows x 6 cols (c4-1 .. c4+4)
    float a[4][6];

    auto loadRow = [&](int t, float* dst) {
        int rr = (t < 0) ? -t : ((t >= H_) ? (2 * H_ - 2 - t) : t);  // reflect pad=1
        const float* rowp = pin + rr * W_;
        float4 m = *(const float4*)(rowp + c4);
        dst[1] = m.x; dst[2] = m.y; dst[3] = m.z; dst[4] = m.w;
        // col c4-1: left neighbor's m.w; lane 0 reflects col -1 -> col 1 = own m.y
        float lv = __shfl(m.w, lane - 1, 64);
        dst[0] = (lane == 0) ? m.y : lv;
        // col c4+4: right neighbor's m.x; lane 63 reflects col 256 -> col 254 = own m.z
        float rv = __shfl(m.x, lane + 1, 64);
        dst[5] = (lane == 63) ? m.z : rv;
    };

    loadRow(r0 - 1, a[0]);
    loadRow(r0,     a[1]);
    loadRow(r0 + 1, a[2]);

#pragma unroll
    for (int j = 0; j < 16; ++j) {
        if (j < 15) loadRow(r0 + j + 2, a[(j + 3) & 3]);   // prefetch next row
        const float* rm1 = a[j & 3];
        const float* rc  = a[(j + 1) & 3];
        const float* rp1 = a[(j + 2) & 3];
        float4 o4;
        float* op = (float*)&o4;
#pragma unroll
        for (int t = 0; t < 4; ++t) {
            op[t] = k[0] * rm1[t] + k[1] * rm1[t + 1] + k[2] * rm1[t + 2]
                  + k[3] * rc[t]  + k[4] * rc[t + 1]  + k[5] * rc[t + 2]
                  + k[6] * rp1[t] + k[7] * rp1[t + 1] + k[8] * rp1[t + 2];
        }
        *(float4*)(pout + (size_t)(r0 + j) * W_ + c4) = o4;
    }
}

extern "C" void kernel_launch(void* const* d_in, const int* in_sizes, int n_in,
                              void* d_out, int out_size, void* d_ws, size_t ws_size,
                              hipStream_t stream) {
    const float* x    = (const float*)d_in[0];   // [8,64,256,256]
    const float* rep  = (const float*)d_in[1];   // [8,512]
    const float* wkey = (const float*)d_in[2];   // [576,512]
    float* out  = (float*)d_out;                 // [8,64,256,256]
    float* kern = (float*)d_ws;                  // 4608 floats scratch

    compute_kern_k<<<1152, 256, 0, stream>>>(rep, wkey, kern);
    // 512 planes * 4 quarter-strips, 256 threads (4 waves x 16-row strips)
    dwconv3x3_strip<<<2048, 256, 0, stream>>>(x, kern, out);
}

// Round 3
// 238.466 us; speedup vs baseline: 1.1106x; 1.0051x over previous
//
#include <hip/hip_runtime.h>

#define B_  8
#define C_  64
#define H_  256
#define W_  256
#define REP_ 512

__global__ __launch_bounds__(256) void compute_kern_k(const float* __restrict__ rep,
                                                      const float* __restrict__ wkey,
                                                      float* __restrict__ kern) {
    int wave = blockIdx.x * 4 + (threadIdx.x >> 6);   // 0..4607
    int lane = threadIdx.x & 63;
    int b = wave / 576;
    int o = wave - b * 576;
    const float* wrow = wkey + (size_t)o * REP_;
    const float* rrow = rep  + (size_t)b * REP_;
    float acc = 0.f;
#pragma unroll
    for (int i = 0; i < REP_ / 64; ++i) {
        int r = lane + i * 64;
        acc += rrow[r] * wrow[r];
    }
#pragma unroll
    for (int off = 32; off > 0; off >>= 1)
        acc += __shfl_xor(acc, off, 64);
    if (lane == 0) {
        float v = acc;
        kern[wave] = v > 0.f ? v : 0.1f * v;   // LeakyReLU(0.1)
    }
}

// 4-wide x 16-tall strip per thread. Raw float4 ring of 6 (prefetch dist ~4)
// DECOUPLED from halo shuffles: shuffle of row r runs 3 iters after r's load
// was issued -> auto-waitcnt becomes vmcnt(3), keeping ~4 loads in flight.
__global__ __launch_bounds__(256) void dwconv3x3_strip(const float* __restrict__ x,
                                                       const float* __restrict__ kern,
                                                       float* __restrict__ out) {
    int plane   = blockIdx.x >> 2;
    int quarter = blockIdx.x & 3;
    int wv   = threadIdx.x >> 6;
    int lane = threadIdx.x & 63;
    int r0 = quarter * 64 + wv * 16;
    int c4 = lane << 2;

    const float* pin  = x   + (size_t)plane * (H_ * W_);
    float*       pout = out + (size_t)plane * (H_ * W_);
    const float* kp   = kern + plane * 9;
    float k[9];
#pragma unroll
    for (int i = 0; i < 9; ++i) k[i] = kp[i];

    // row index helper (reflect pad=1); i = row - (r0-1), rows r0-1 .. r0+16
    auto loadRaw = [&](int i) -> float4 {
        int t = r0 - 1 + i;
        int rr = (t < 0) ? -t : ((t >= H_) ? (2 * H_ - 2 - t) : t);
        return *(const float4*)(pin + rr * W_ + c4);
    };
    // halo expand: raw float4 -> 6-wide row (cols c4-1 .. c4+4)
    auto shufRow = [&](float4 m, float* dst) {
        dst[1] = m.x; dst[2] = m.y; dst[3] = m.z; dst[4] = m.w;
        float lv = __shfl(m.w, lane - 1, 64);
        dst[0] = (lane == 0) ? m.y : lv;
        float rv = __shfl(m.x, lane + 1, 64);
        dst[5] = (lane == 63) ? m.z : rv;
    };

    float4 raw[6];                 // slot = i % 6
#pragma unroll
    for (int i = 0; i < 6; ++i) raw[i] = loadRaw(i);

    float w[3][6];                 // row t lives in w[(t - (r0-1)) % 3]
    shufRow(raw[0], w[0]);         // row r0-1
    shufRow(raw[1], w[1]);         // row r0
    shufRow(raw[2], w[2]);         // row r0+1

#pragma unroll
    for (int j = 0; j < 16; ++j) {
        if (j < 12) raw[j % 6] = loadRaw(j + 6);   // rows up to r0+16 (i=17 at j=11)

        const float* rm1 = w[j % 3];
        const float* rc  = w[(j + 1) % 3];
        const float* rp1 = w[(j + 2) % 3];
        float4 o4;
        float* op = (float*)&o4;
#pragma unroll
        for (int t = 0; t < 4; ++t) {
            op[t] = k[0] * rm1[t] + k[1] * rm1[t + 1] + k[2] * rm1[t + 2]
                  + k[3] * rc[t]  + k[4] * rc[t + 1]  + k[5] * rc[t + 2]
                  + k[6] * rp1[t] + k[7] * rp1[t + 1] + k[8] * rp1[t + 2];
        }
        *(float4*)(pout + (size_t)(r0 + j) * W_ + c4) = o4;

        if (j < 15) shufRow(raw[(j + 3) % 6], w[j % 3]);  // prepare row r0+j+2
    }
}

extern "C" void kernel_launch(void* const* d_in, const int* in_sizes, int n_in,
                              void* d_out, int out_size, void* d_ws, size_t ws_size,
                              hipStream_t stream) {
    const float* x    = (const float*)d_in[0];   // [8,64,256,256]
    const float* rep  = (const float*)d_in[1];   // [8,512]
    const float* wkey = (const float*)d_in[2];   // [576,512]
    float* out  = (float*)d_out;                 // [8,64,256,256]
    float* kern = (float*)d_ws;                  // 4608 floats scratch

    compute_kern_k<<<1152, 256, 0, stream>>>(rep, wkey, kern);
    dwconv3x3_strip<<<2048, 256, 0, stream>>>(x, kern, out);
}

// Round 4
// 238.081 us; speedup vs baseline: 1.1124x; 1.0016x over previous
//
#include <hip/hip_runtime.h>

#define B_  8
#define C_  64
#define H_  256
#define W_  256
#define REP_ 512

__global__ __launch_bounds__(256) void compute_kern_k(const float* __restrict__ rep,
                                                      const float* __restrict__ wkey,
                                                      float* __restrict__ kern) {
    int wave = blockIdx.x * 4 + (threadIdx.x >> 6);   // 0..4607
    int lane = threadIdx.x & 63;
    int b = wave / 576;
    int o = wave - b * 576;
    const float* wrow = wkey + (size_t)o * REP_;
    const float* rrow = rep  + (size_t)b * REP_;
    float acc = 0.f;
#pragma unroll
    for (int i = 0; i < REP_ / 64; ++i) {
        int r = lane + i * 64;
        acc += rrow[r] * wrow[r];
    }
#pragma unroll
    for (int off = 32; off > 0; off >>= 1)
        acc += __shfl_xor(acc, off, 64);
    if (lane == 0) {
        float v = acc;
        kern[wave] = v > 0.f ? v : 0.1f * v;   // LeakyReLU(0.1)
    }
}

// Phase-separated: (1) load ALL 10 rows (float4 each) back-to-back -> 10 KB
// in flight per wave, no stores polluting the vmcnt queue; (2) halo-expand
// all rows via shuffles; (3) compute + store 8 output rows from registers.
__global__ __launch_bounds__(256) void dwconv3x3_strip8(const float* __restrict__ x,
                                                        const float* __restrict__ kern,
                                                        float* __restrict__ out) {
    int plane = blockIdx.x >> 3;            // b*64 + c
    int strip = blockIdx.x & 7;             // 32-row strip of the plane
    int wv   = threadIdx.x >> 6;            // wave: 8-row sub-strip
    int lane = threadIdx.x & 63;
    int r0 = strip * 32 + wv * 8;           // first output row
    int c4 = lane << 2;                     // this lane's 4 columns

    const float* pin  = x   + (size_t)plane * (H_ * W_);
    float*       pout = out + (size_t)plane * (H_ * W_);
    const float* kp   = kern + plane * 9;
    float k[9];
#pragma unroll
    for (int i = 0; i < 9; ++i) k[i] = kp[i];   // block-uniform

    // ---- phase 1: all loads, back-to-back ----
    float4 raw[10];
#pragma unroll
    for (int i = 0; i < 10; ++i) {
        int t = r0 - 1 + i;
        int rr = (t < 0) ? -t : ((t >= H_) ? (2 * H_ - 2 - t) : t);  // reflect
        raw[i] = *(const float4*)(pin + rr * W_ + c4);
    }

    // ---- phase 2: halo expansion, registers only ----
    float lft[10], rgt[10];
#pragma unroll
    for (int i = 0; i < 10; ++i) {
        float lv = __shfl(raw[i].w, lane - 1, 64);
        lft[i] = (lane == 0) ? raw[i].y : lv;            // col -1 -> col 1
        float rv = __shfl(raw[i].x, lane + 1, 64);
        rgt[i] = (lane == 63) ? raw[i].z : rv;           // col 256 -> col 254
    }

    // element accessor: row i, window col t in [0,6)
    auto e = [&](int i, int t) -> float {
        if (t == 0) return lft[i];
        if (t == 5) return rgt[i];
        return ((const float*)&raw[i])[t - 1];
    };

    // ---- phase 3: compute + store, no loads ----
#pragma unroll
    for (int j = 0; j < 8; ++j) {
        float4 o4;
        float* op = (float*)&o4;
#pragma unroll
        for (int t = 0; t < 4; ++t) {
            op[t] = k[0] * e(j, t)     + k[1] * e(j, t + 1)     + k[2] * e(j, t + 2)
                  + k[3] * e(j + 1, t) + k[4] * e(j + 1, t + 1) + k[5] * e(j + 1, t + 2)
                  + k[6] * e(j + 2, t) + k[7] * e(j + 2, t + 1) + k[8] * e(j + 2, t + 2);
        }
        *(float4*)(pout + (size_t)(r0 + j) * W_ + c4) = o4;
    }
}

extern "C" void kernel_launch(void* const* d_in, const int* in_sizes, int n_in,
                              void* d_out, int out_size, void* d_ws, size_t ws_size,
                              hipStream_t stream) {
    const float* x    = (const float*)d_in[0];   // [8,64,256,256]
    const float* rep  = (const float*)d_in[1];   // [8,512]
    const float* wkey = (const float*)d_in[2];   // [576,512]
    float* out  = (float*)d_out;                 // [8,64,256,256]
    float* kern = (float*)d_ws;                  // 4608 floats scratch

    compute_kern_k<<<1152, 256, 0, stream>>>(rep, wkey, kern);
    // 512 planes * 8 strips, 256 threads (4 waves x 8-row sub-strips)
    dwconv3x3_strip8<<<4096, 256, 0, stream>>>(x, kern, out);
}